// Round 1
// baseline (592.799 us; speedup 1.0000x reference)
//
#include <hip/hip_runtime.h>

#define B 64
#define N 1025
#define NPAD 1028
#define C 768
#define H 12
#define HD 64

__device__ __forceinline__ float wave_reduce_add(float v) {
    #pragma unroll
    for (int m = 1; m < 64; m <<= 1) v += __shfl_xor(v, m, 64);
    return v;
}

// ---------------------------------------------------------------------------
// k_qproj: q[b][c] = 0.125 * (cls[b] . qW[c,:] + qb[c])
// grid (16 btiles, 12 ctiles), block 256 (4 waves). Wave w owns batch bt*4+w.
// ---------------------------------------------------------------------------
__global__ __launch_bounds__(256) void k_qproj(const float* __restrict__ x,
                                               const float* __restrict__ qW,
                                               const float* __restrict__ qb,
                                               float* __restrict__ qout) {
    __shared__ float cls[4 * C];
    int bt = blockIdx.x, ct = blockIdx.y, tid = threadIdx.x;
    for (int i = tid; i < 4 * C; i += 256) {
        int bl = i / C, c = i % C;
        cls[i] = x[(size_t)(bt * 4 + bl) * N * C + c];
    }
    __syncthreads();
    int w = tid >> 6, lane = tid & 63;
    int b = bt * 4 + w;
    const float* clsrow = &cls[w * C];
    for (int cl = 0; cl < 64; ++cl) {
        int c = ct * 64 + cl;
        const float4* wr = (const float4*)(qW + (size_t)c * C + lane * 12);
        const float4* xr = (const float4*)(clsrow + lane * 12);
        float acc = 0.f;
        #pragma unroll
        for (int s = 0; s < 3; ++s) {
            float4 a = wr[s], v = xr[s];
            acc += a.x * v.x + a.y * v.y + a.z * v.z + a.w * v.w;
        }
        acc = wave_reduce_add(acc);
        if (lane == 0) qout[b * C + c] = 0.125f * (acc + qb[c]);
    }
}

// ---------------------------------------------------------------------------
// k_qk: qk[b][h][c'] = sum_{i<64} q[b][h*64+i] * kW[h*64+i][c']
//       qkb[b][h]    = sum_{i<64} q[b][h*64+i] * kb[h*64+i]
// grid (16 btiles, 12 heads), block 192 (thread owns float4 of c').
// ---------------------------------------------------------------------------
__global__ __launch_bounds__(192) void k_qk(const float* __restrict__ q,
                                            const float* __restrict__ kW,
                                            const float* __restrict__ kb,
                                            float* __restrict__ qk,
                                            float* __restrict__ qkb) {
    int bt = blockIdx.x, h = blockIdx.y, tid = threadIdx.x;
    float4 acc[4] = {};
    for (int i = 0; i < HD; ++i) {
        int row = h * HD + i;
        float4 kv = *(const float4*)(kW + (size_t)row * C + tid * 4);
        #pragma unroll
        for (int bl = 0; bl < 4; ++bl) {
            float qv = q[(bt * 4 + bl) * C + row];  // uniform -> s_load
            acc[bl].x += qv * kv.x; acc[bl].y += qv * kv.y;
            acc[bl].z += qv * kv.z; acc[bl].w += qv * kv.w;
        }
    }
    #pragma unroll
    for (int bl = 0; bl < 4; ++bl) {
        int b = bt * 4 + bl;
        *(float4*)(qk + ((size_t)b * H + h) * C + tid * 4) = acc[bl];
    }
    if (tid < 4) {
        int b = bt * 4 + tid;
        float s = 0.f;
        for (int i = 0; i < HD; ++i) s += q[b * C + h * HD + i] * kb[h * HD + i];
        qkb[b * H + h] = s;
    }
}

// ---------------------------------------------------------------------------
// k_scores: sc[b][h][n] = x[b,n,:] . qk[b,h,:]   (bias added later in k3)
// x pass 1. grid (17 row-tiles, 64 b), block 256 (4 waves x 16 rows).
// Wave layout: lane = r*16 + c16; lane owns rows rowbase+r*4+j (j=0..3),
// c-slice c16*4 within each 64-wide cc chunk. Register accum, no LDS.
// ---------------------------------------------------------------------------
__global__ __launch_bounds__(256, 4) void k_scores(const float* __restrict__ x,
                                                   const float* __restrict__ qk,
                                                   float* __restrict__ sc) {
    int tile = blockIdx.x, b = blockIdx.y, tid = threadIdx.x;
    int w = tid >> 6, lane = tid & 63;
    int c16 = lane & 15, r = lane >> 4;
    int rowbase = tile * 64 + w * 16 + r * 4;
    const float* xb = x + (size_t)b * N * C;
    const float* qkbase = qk + (size_t)b * H * C;
    float acc[4][12] = {};
    for (int cc = 0; cc < C; cc += 64) {
        int cofs = cc + c16 * 4;
        float4 xv[4];
        #pragma unroll
        for (int j = 0; j < 4; ++j) {
            int row = rowbase + j;
            xv[j] = (row < N) ? *(const float4*)(xb + (size_t)row * C + cofs)
                              : make_float4(0.f, 0.f, 0.f, 0.f);
        }
        #pragma unroll
        for (int h = 0; h < 12; ++h) {
            float4 qv = *(const float4*)(qkbase + h * C + cofs);
            #pragma unroll
            for (int j = 0; j < 4; ++j)
                acc[j][h] += xv[j].x * qv.x + xv[j].y * qv.y +
                             xv[j].z * qv.z + xv[j].w * qv.w;
        }
    }
    #pragma unroll
    for (int j = 0; j < 4; ++j)
        #pragma unroll
        for (int h = 0; h < 12; ++h) {
            float v = acc[j][h];
            v += __shfl_xor(v, 1); v += __shfl_xor(v, 2);
            v += __shfl_xor(v, 4); v += __shfl_xor(v, 8);
            acc[j][h] = v;
        }
    if (c16 == 0) {
        #pragma unroll
        for (int j = 0; j < 4; ++j) {
            int row = rowbase + j;
            if (row < N) {
                #pragma unroll
                for (int h = 0; h < 12; ++h)
                    sc[((size_t)b * H + h) * NPAD + row] = acc[j][h];
            }
        }
    }
}

// ---------------------------------------------------------------------------
// k_softmix: per batch b: a1 = (s+qkb) + w1W@(s+qkb) + w1b; p = softmax(a1);
// a2 = p + w2W@p + w2b; write a2 transposed [n][h]; s2[g] = sum_n a2[g][n].
// grid 64, block 256. Whole 12x1028 score block lives in LDS.
// ---------------------------------------------------------------------------
__global__ __launch_bounds__(256) void k_softmix(const float* __restrict__ sc,
                                                 const float* __restrict__ qkbias,
                                                 const float* __restrict__ w1W,
                                                 const float* __restrict__ w1b,
                                                 const float* __restrict__ w2W,
                                                 const float* __restrict__ w2b,
                                                 float* __restrict__ a2t,
                                                 float* __restrict__ s2) {
    __shared__ float sb[12 * NPAD];
    __shared__ float w1s[144], w1bs[12], w2s[144], w2bs[12];
    __shared__ float ms[12], invs[12], red[12];
    int b = blockIdx.x, tid = threadIdx.x;
    if (tid < 144) { w1s[tid] = w1W[tid]; w2s[tid] = w2W[tid]; }
    if (tid < 12)  { w1bs[tid] = w1b[tid]; w2bs[tid] = w2b[tid]; red[tid] = 0.f; }
    for (int i = tid; i < 12 * NPAD; i += 256) {
        int h = i / NPAD, n = i % NPAD;
        sb[i] = (n < N) ? sc[((size_t)b * H + h) * NPAD + n] + qkbias[b * H + h] : 0.f;
    }
    __syncthreads();
    // mix1 (column-independent, in place)
    for (int n = tid; n < N; n += 256) {
        float p[12], o[12];
        #pragma unroll
        for (int h = 0; h < 12; ++h) p[h] = sb[h * NPAD + n];
        #pragma unroll
        for (int g = 0; g < 12; ++g) {
            float a = p[g] + w1bs[g];
            #pragma unroll
            for (int h = 0; h < 12; ++h) a += w1s[g * 12 + h] * p[h];
            o[g] = a;
        }
        #pragma unroll
        for (int g = 0; g < 12; ++g) sb[g * NPAD + n] = o[g];
    }
    __syncthreads();
    // per-row max and sum(exp)
    int w = tid >> 6, lane = tid & 63;
    for (int g = w; g < 12; g += 4) {
        float m = -1e30f;
        for (int n = lane; n < N; n += 64) m = fmaxf(m, sb[g * NPAD + n]);
        #pragma unroll
        for (int k = 1; k < 64; k <<= 1) m = fmaxf(m, __shfl_xor(m, k, 64));
        float s = 0.f;
        for (int n = lane; n < N; n += 64) s += __expf(sb[g * NPAD + n] - m);
        s = wave_reduce_add(s);
        if (lane == 0) { ms[g] = m; invs[g] = 1.f / s; }
    }
    __syncthreads();
    // softmax + mix2 + transposed write + column sums
    float cs[12] = {};
    for (int n = tid; n < N; n += 256) {
        float p[12], o[12];
        #pragma unroll
        for (int h = 0; h < 12; ++h) p[h] = __expf(sb[h * NPAD + n] - ms[h]) * invs[h];
        #pragma unroll
        for (int g = 0; g < 12; ++g) {
            float a = p[g] + w2bs[g];
            #pragma unroll
            for (int h = 0; h < 12; ++h) a += w2s[g * 12 + h] * p[h];
            o[g] = a; cs[g] += a;
        }
        float* dst = a2t + ((size_t)b * N + n) * 12;
        #pragma unroll
        for (int g = 0; g < 12; ++g) dst[g] = o[g];
    }
    #pragma unroll
    for (int g = 0; g < 12; ++g) cs[g] = wave_reduce_add(cs[g]);
    if (lane == 0) {
        #pragma unroll
        for (int g = 0; g < 12; ++g) atomicAdd(&red[g], cs[g]);
    }
    __syncthreads();
    if (tid < 12) s2[b * H + tid] = red[tid];
}

// ---------------------------------------------------------------------------
// k_ysum: yp[k][b][h][c] = sum_{n in chunk k} a2[b][h][n] * x[b][n][c]
// x pass 2. grid (8 nchunks, 64 b), block 192 (thread owns float4 of c,
// block covers the full 3KB row -> perfectly coalesced). a2 reads uniform.
// ---------------------------------------------------------------------------
#define FMA4(d, s) { d.x += (s) * xv.x; d.y += (s) * xv.y; d.z += (s) * xv.z; d.w += (s) * xv.w; }
__global__ __launch_bounds__(192, 4) void k_ysum(const float* __restrict__ x,
                                                 const float* __restrict__ a2t,
                                                 float* __restrict__ yp) {
    int k = blockIdx.x, b = blockIdx.y, tid = threadIdx.x;
    int nlo = k * 128, nhi = (k == 7) ? N : nlo + 128;
    const float* xb = x + (size_t)b * N * C + tid * 4;
    float4 acc[12] = {};
    for (int n = nlo; n < nhi; ++n) {
        float4 xv = *(const float4*)(xb + (size_t)n * C);
        const float4* ar = (const float4*)(a2t + ((size_t)b * N + n) * 12);
        float4 a0 = ar[0], a1 = ar[1], a2 = ar[2];
        FMA4(acc[0], a0.x); FMA4(acc[1], a0.y); FMA4(acc[2], a0.z); FMA4(acc[3], a0.w);
        FMA4(acc[4], a1.x); FMA4(acc[5], a1.y); FMA4(acc[6], a1.z); FMA4(acc[7], a1.w);
        FMA4(acc[8], a2.x); FMA4(acc[9], a2.y); FMA4(acc[10], a2.z); FMA4(acc[11], a2.w);
    }
    #pragma unroll
    for (int h = 0; h < 12; ++h)
        *(float4*)(yp + (((size_t)k * B + b) * H + h) * C + tid * 4) = acc[h];
}

// ---------------------------------------------------------------------------
// k_zproj: z[b][c] = ybar[b,h(c),:] . vW[c,:] + vb[c]*s2[b,h(c)],
// ybar = sum of 8 yp partials. grid (16 btiles, 12 heads), block 256.
// ---------------------------------------------------------------------------
__global__ __launch_bounds__(256) void k_zproj(const float* __restrict__ yp,
                                               const float* __restrict__ vW,
                                               const float* __restrict__ vb,
                                               const float* __restrict__ s2,
                                               float* __restrict__ z) {
    __shared__ float ys[4 * C];
    int bt = blockIdx.x, h = blockIdx.y, tid = threadIdx.x;
    for (int i = tid; i < 4 * C; i += 256) {
        int bl = i / C, cp = i % C;
        int b = bt * 4 + bl;
        float s = 0.f;
        #pragma unroll
        for (int k = 0; k < 8; ++k) s += yp[(((size_t)k * B + b) * H + h) * C + cp];
        ys[i] = s;
    }
    __syncthreads();
    int w = tid >> 6, lane = tid & 63;
    int b = bt * 4 + w;
    float sv = s2[b * H + h];
    const float* yrow = &ys[w * C];
    for (int cl = 0; cl < 64; ++cl) {
        int c = h * 64 + cl;
        const float4* wr = (const float4*)(vW + (size_t)c * C + lane * 12);
        const float4* yr = (const float4*)(yrow + lane * 12);
        float acc = 0.f;
        #pragma unroll
        for (int s = 0; s < 3; ++s) {
            float4 a = wr[s], v = yr[s];
            acc += a.x * v.x + a.y * v.y + a.z * v.z + a.w * v.w;
        }
        acc = wave_reduce_add(acc);
        if (lane == 0) z[b * C + c] = acc + vb[c] * sv;
    }
}

// ---------------------------------------------------------------------------
// k_out: out[b][c] = z[b,:] . projW[c,:] + projb[c]
// grid (16 btiles, 12 ctiles), block 256.
// ---------------------------------------------------------------------------
__global__ __launch_bounds__(256) void k_out(const float* __restrict__ z,
                                             const float* __restrict__ pW,
                                             const float* __restrict__ pb,
                                             float* __restrict__ out) {
    __shared__ float zs[4 * C];
    int bt = blockIdx.x, ct = blockIdx.y, tid = threadIdx.x;
    for (int i = tid; i < 4 * C; i += 256) zs[i] = z[(size_t)bt * 4 * C + i];
    __syncthreads();
    int w = tid >> 6, lane = tid & 63;
    int b = bt * 4 + w;
    for (int cl = 0; cl < 64; ++cl) {
        int c = ct * 64 + cl;
        const float4* wr = (const float4*)(pW + (size_t)c * C + lane * 12);
        const float4* zr = (const float4*)(zs + w * C + lane * 12);
        float acc = 0.f;
        #pragma unroll
        for (int s = 0; s < 3; ++s) {
            float4 a = wr[s], v = zr[s];
            acc += a.x * v.x + a.y * v.y + a.z * v.z + a.w * v.w;
        }
        acc = wave_reduce_add(acc);
        if (lane == 0) out[b * C + c] = acc + pb[c];
    }
}

extern "C" void kernel_launch(void* const* d_in, const int* in_sizes, int n_in,
                              void* d_out, int out_size, void* d_ws, size_t ws_size,
                              hipStream_t stream) {
    const float* x    = (const float*)d_in[0];
    const float* qW   = (const float*)d_in[1];
    const float* qb   = (const float*)d_in[2];
    const float* kW   = (const float*)d_in[3];
    const float* kb   = (const float*)d_in[4];
    const float* vW   = (const float*)d_in[5];
    const float* vb   = (const float*)d_in[6];
    const float* w1W  = (const float*)d_in[7];
    const float* w1b  = (const float*)d_in[8];
    const float* w2W  = (const float*)d_in[9];
    const float* w2b  = (const float*)d_in[10];
    const float* pW   = (const float*)d_in[11];
    const float* pb   = (const float*)d_in[12];
    float* out = (float*)d_out;

    float* ws   = (float*)d_ws;
    float* qk   = ws + 0;        // 64*12*768        = 589824
    float* qkb  = ws + 589824;   // 64*12            = 768
    float* q    = ws + 590592;   // 64*768           = 49152
    float* sc   = ws + 639744;   // 64*12*1028       = 789504
    float* a2t  = ws + 1429248;  // 64*1025*12       = 787200
    float* s2   = ws + 2216448;  // 64*12            = 768
    float* yp   = ws + 2217216;  // 8*64*12*768      = 4718592
    float* z    = ws + 6935808;  // 64*768           = 49152
    // total 6984960 floats = 27.9 MB

    k_qproj  <<<dim3(16, 12), 256, 0, stream>>>(x, qW, qb, q);
    k_qk     <<<dim3(16, 12), 192, 0, stream>>>(q, kW, kb, qk, qkb);
    k_scores <<<dim3(17, 64), 256, 0, stream>>>(x, qk, sc);
    k_softmix<<<64, 256, 0, stream>>>(sc, qkb, w1W, w1b, w2W, w2b, a2t, s2);
    k_ysum   <<<dim3(8, 64), 192, 0, stream>>>(x, a2t, yp);
    k_zproj  <<<dim3(16, 12), 256, 0, stream>>>(yp, vW, vb, s2, z);
    k_out    <<<dim3(16, 12), 256, 0, stream>>>(z, pW, pb, out);
}

// Round 2
// 466.624 us; speedup vs baseline: 1.2704x; 1.2704x over previous
//
#include <hip/hip_runtime.h>

#define B 64
#define N 1025
#define NPAD 1028
#define C 768
#define H 12
#define HD 64

__device__ __forceinline__ float wave_reduce_add(float v) {
    #pragma unroll
    for (int m = 1; m < 64; m <<= 1) v += __shfl_xor(v, m, 64);
    return v;
}

// ---------------------------------------------------------------------------
// k_qproj: q[b][c] = 0.125 * (cls[b] . qW[c,:] + qb[c])
// grid (16 btiles, 48 ctiles of 16), block 256 (4 waves). Wave w = batch.
// ---------------------------------------------------------------------------
__global__ __launch_bounds__(256) void k_qproj(const float* __restrict__ x,
                                               const float* __restrict__ qW,
                                               const float* __restrict__ qb,
                                               float* __restrict__ qout) {
    __shared__ float cls[4 * C];
    int bt = blockIdx.x, ct = blockIdx.y, tid = threadIdx.x;
    for (int i = tid; i < 768; i += 256) {   // 768 float4 = 4 rows x 192
        int bl = i / 192, c4 = i % 192;
        ((float4*)cls)[i] = ((const float4*)(x + (size_t)(bt * 4 + bl) * N * C))[c4];
    }
    __syncthreads();
    int w = tid >> 6, lane = tid & 63;
    int b = bt * 4 + w;
    const float* clsrow = &cls[w * C];
    for (int cl = 0; cl < 16; ++cl) {
        int c = ct * 16 + cl;
        const float4* wr = (const float4*)(qW + (size_t)c * C + lane * 12);
        const float4* xr = (const float4*)(clsrow + lane * 12);
        float acc = 0.f;
        #pragma unroll
        for (int s = 0; s < 3; ++s) {
            float4 a = wr[s], v = xr[s];
            acc += a.x * v.x + a.y * v.y + a.z * v.z + a.w * v.w;
        }
        acc = wave_reduce_add(acc);
        if (lane == 0) qout[b * C + c] = 0.125f * (acc + qb[c]);
    }
}

// ---------------------------------------------------------------------------
// k_qk: qk[b][h][c'] = sum_{i<64} q[b][h*64+i] * kW[h*64+i][c']
//       qkb[b][h]    = sum_{i<64} q[b][h*64+i] * kb[h*64+i]
// grid (16 btiles, 12 heads), block 256. Threads <192 do main (float4 of c');
// each wave w also computes qkb for batch bt*4+w by 64-lane reduce.
// ---------------------------------------------------------------------------
__global__ __launch_bounds__(256) void k_qk(const float* __restrict__ q,
                                            const float* __restrict__ kW,
                                            const float* __restrict__ kb,
                                            float* __restrict__ qk,
                                            float* __restrict__ qkb) {
    int bt = blockIdx.x, h = blockIdx.y, tid = threadIdx.x;
    if (tid < 192) {
        float4 acc[4] = {};
        #pragma unroll 4
        for (int i = 0; i < HD; ++i) {
            int row = h * HD + i;
            float4 kv = *(const float4*)(kW + (size_t)row * C + tid * 4);
            #pragma unroll
            for (int bl = 0; bl < 4; ++bl) {
                float qv = q[(bt * 4 + bl) * C + row];  // uniform -> s_load
                acc[bl].x += qv * kv.x; acc[bl].y += qv * kv.y;
                acc[bl].z += qv * kv.z; acc[bl].w += qv * kv.w;
            }
        }
        #pragma unroll
        for (int bl = 0; bl < 4; ++bl) {
            int b = bt * 4 + bl;
            *(float4*)(qk + ((size_t)b * H + h) * C + tid * 4) = acc[bl];
        }
    }
    int w = tid >> 6, lane = tid & 63;
    int b = bt * 4 + w;
    float v = q[b * C + h * HD + lane] * kb[h * HD + lane];
    v = wave_reduce_add(v);
    if (lane == 0) qkb[b * H + h] = v;
}

// ---------------------------------------------------------------------------
// k_scores: sc[b][h][n] = x[b,n,:] . qk[b,h,:]   (bias added later)
// x pass 1. grid (17 row-tiles, 64 b), block 256 (4 waves x 16 rows).
// qk[b] staged in LDS (36 KB -> 4 blocks/CU). cc unrolled x2: 8 x-loads
// (128 B/lane) in flight -> HBM MLP. Lane = r*16+c16; 4 rows/lane-row.
// ---------------------------------------------------------------------------
__global__ __launch_bounds__(256) void k_scores(const float* __restrict__ x,
                                                const float* __restrict__ qk,
                                                float* __restrict__ sc) {
    __shared__ float qs[12 * C];   // 36 KB
    int tile = blockIdx.x, b = blockIdx.y, tid = threadIdx.x;
    const float4* qksrc = (const float4*)(qk + (size_t)b * H * C);
    for (int i = tid; i < 2304; i += 256) ((float4*)qs)[i] = qksrc[i];
    __syncthreads();
    int w = tid >> 6, lane = tid & 63;
    int c16 = lane & 15, r = lane >> 4;
    int rowbase = tile * 64 + w * 16 + r * 4;
    const float* xb = x + (size_t)b * N * C;
    float acc[4][12] = {};
    for (int cc = 0; cc < C; cc += 128) {
        int c0 = cc + c16 * 4, c1 = c0 + 64;
        float4 xv0[4], xv1[4];
        #pragma unroll
        for (int j = 0; j < 4; ++j) {
            int row = rowbase + j;
            const float* xr = xb + (size_t)row * C;
            xv0[j] = (row < N) ? *(const float4*)(xr + c0) : make_float4(0.f,0.f,0.f,0.f);
            xv1[j] = (row < N) ? *(const float4*)(xr + c1) : make_float4(0.f,0.f,0.f,0.f);
        }
        #pragma unroll
        for (int h = 0; h < 12; ++h) {
            float4 q0 = *(const float4*)(qs + h * C + c0);
            float4 q1 = *(const float4*)(qs + h * C + c1);
            #pragma unroll
            for (int j = 0; j < 4; ++j) {
                acc[j][h] += xv0[j].x * q0.x + xv0[j].y * q0.y +
                             xv0[j].z * q0.z + xv0[j].w * q0.w;
                acc[j][h] += xv1[j].x * q1.x + xv1[j].y * q1.y +
                             xv1[j].z * q1.z + xv1[j].w * q1.w;
            }
        }
    }
    #pragma unroll
    for (int j = 0; j < 4; ++j)
        #pragma unroll
        for (int h = 0; h < 12; ++h) {
            float v = acc[j][h];
            v += __shfl_xor(v, 1); v += __shfl_xor(v, 2);
            v += __shfl_xor(v, 4); v += __shfl_xor(v, 8);
            acc[j][h] = v;
        }
    if (c16 == 0) {
        #pragma unroll
        for (int j = 0; j < 4; ++j) {
            int row = rowbase + j;
            if (row < N) {
                #pragma unroll
                for (int h = 0; h < 12; ++h)
                    sc[((size_t)b * H + h) * NPAD + row] = acc[j][h];
            }
        }
    }
}

// ---------------------------------------------------------------------------
// k_softmix: per batch b: a1 = (s+qkb) + w1W@(s+qkb) + w1b; p = softmax(a1);
// a2 = p + w2W@p + w2b; write a2 transposed [n][h]; s2[g] = sum_n a2[g][n].
// grid 64, block 256. Whole 12x1028 score block lives in LDS.
// ---------------------------------------------------------------------------
__global__ __launch_bounds__(256) void k_softmix(const float* __restrict__ sc,
                                                 const float* __restrict__ qkbias,
                                                 const float* __restrict__ w1W,
                                                 const float* __restrict__ w1b,
                                                 const float* __restrict__ w2W,
                                                 const float* __restrict__ w2b,
                                                 float* __restrict__ a2t,
                                                 float* __restrict__ s2) {
    __shared__ float sb[12 * NPAD];
    __shared__ float w1s[144], w1bs[12], w2s[144], w2bs[12];
    __shared__ float ms[12], invs[12], red[12];
    int b = blockIdx.x, tid = threadIdx.x;
    if (tid < 144) { w1s[tid] = w1W[tid]; w2s[tid] = w2W[tid]; }
    if (tid < 12)  { w1bs[tid] = w1b[tid]; w2bs[tid] = w2b[tid]; red[tid] = 0.f; }
    for (int i = tid; i < 12 * NPAD; i += 256) {
        int h = i / NPAD, n = i % NPAD;
        sb[i] = (n < N) ? sc[((size_t)b * H + h) * NPAD + n] + qkbias[b * H + h] : 0.f;
    }
    __syncthreads();
    for (int n = tid; n < N; n += 256) {
        float p[12], o[12];
        #pragma unroll
        for (int h = 0; h < 12; ++h) p[h] = sb[h * NPAD + n];
        #pragma unroll
        for (int g = 0; g < 12; ++g) {
            float a = p[g] + w1bs[g];
            #pragma unroll
            for (int h = 0; h < 12; ++h) a += w1s[g * 12 + h] * p[h];
            o[g] = a;
        }
        #pragma unroll
        for (int g = 0; g < 12; ++g) sb[g * NPAD + n] = o[g];
    }
    __syncthreads();
    int w = tid >> 6, lane = tid & 63;
    for (int g = w; g < 12; g += 4) {
        float m = -1e30f;
        for (int n = lane; n < N; n += 64) m = fmaxf(m, sb[g * NPAD + n]);
        #pragma unroll
        for (int k = 1; k < 64; k <<= 1) m = fmaxf(m, __shfl_xor(m, k, 64));
        float s = 0.f;
        for (int n = lane; n < N; n += 64) s += __expf(sb[g * NPAD + n] - m);
        s = wave_reduce_add(s);
        if (lane == 0) { ms[g] = m; invs[g] = 1.f / s; }
    }
    __syncthreads();
    float cs[12] = {};
    for (int n = tid; n < N; n += 256) {
        float p[12], o[12];
        #pragma unroll
        for (int h = 0; h < 12; ++h) p[h] = __expf(sb[h * NPAD + n] - ms[h]) * invs[h];
        #pragma unroll
        for (int g = 0; g < 12; ++g) {
            float a = p[g] + w2bs[g];
            #pragma unroll
            for (int h = 0; h < 12; ++h) a += w2s[g * 12 + h] * p[h];
            o[g] = a; cs[g] += a;
        }
        float* dst = a2t + ((size_t)b * N + n) * 12;
        #pragma unroll
        for (int g = 0; g < 12; ++g) dst[g] = o[g];
    }
    #pragma unroll
    for (int g = 0; g < 12; ++g) cs[g] = wave_reduce_add(cs[g]);
    if (lane == 0) {
        #pragma unroll
        for (int g = 0; g < 12; ++g) atomicAdd(&red[g], cs[g]);
    }
    __syncthreads();
    if (tid < 12) s2[b * H + tid] = red[tid];
}

// ---------------------------------------------------------------------------
// k_ysum: yp[k][b][h][c] = sum_{n in chunk k} a2[b][h][n] * x[b][n][c]
// x pass 2. grid (8 nchunks, 64 b), block 192. a2t chunk staged in LDS;
// n unrolled x4 -> 4 x-loads (64 B/lane) in flight.
// ---------------------------------------------------------------------------
#define FMA4(d, s, xv) { d.x += (s) * xv.x; d.y += (s) * xv.y; d.z += (s) * xv.z; d.w += (s) * xv.w; }
__global__ __launch_bounds__(192) void k_ysum(const float* __restrict__ x,
                                              const float* __restrict__ a2t,
                                              float* __restrict__ yp) {
    __shared__ float as_[129 * 12];
    int k = blockIdx.x, b = blockIdx.y, tid = threadIdx.x;
    int nlo = k * 128, nn = (k == 7) ? 129 : 128;
    const float4* ab = (const float4*)(a2t + ((size_t)b * N + nlo) * 12);
    for (int i = tid; i < nn * 3; i += 192) ((float4*)as_)[i] = ab[i];
    __syncthreads();
    const float* xb = x + ((size_t)b * N + nlo) * C + tid * 4;
    float4 acc[12] = {};
    int n = 0;
    for (; n + 4 <= nn; n += 4) {
        float4 xv[4];
        #pragma unroll
        for (int u = 0; u < 4; ++u)
            xv[u] = *(const float4*)(xb + (size_t)(n + u) * C);
        #pragma unroll
        for (int u = 0; u < 4; ++u) {
            const float4* ar = (const float4*)(as_ + (n + u) * 12);
            float4 a0 = ar[0], a1 = ar[1], a2 = ar[2];
            FMA4(acc[0], a0.x, xv[u]); FMA4(acc[1], a0.y, xv[u]); FMA4(acc[2], a0.z, xv[u]); FMA4(acc[3], a0.w, xv[u]);
            FMA4(acc[4], a1.x, xv[u]); FMA4(acc[5], a1.y, xv[u]); FMA4(acc[6], a1.z, xv[u]); FMA4(acc[7], a1.w, xv[u]);
            FMA4(acc[8], a2.x, xv[u]); FMA4(acc[9], a2.y, xv[u]); FMA4(acc[10], a2.z, xv[u]); FMA4(acc[11], a2.w, xv[u]);
        }
    }
    for (; n < nn; ++n) {
        float4 xv = *(const float4*)(xb + (size_t)n * C);
        const float4* ar = (const float4*)(as_ + n * 12);
        float4 a0 = ar[0], a1 = ar[1], a2 = ar[2];
        FMA4(acc[0], a0.x, xv); FMA4(acc[1], a0.y, xv); FMA4(acc[2], a0.z, xv); FMA4(acc[3], a0.w, xv);
        FMA4(acc[4], a1.x, xv); FMA4(acc[5], a1.y, xv); FMA4(acc[6], a1.z, xv); FMA4(acc[7], a1.w, xv);
        FMA4(acc[8], a2.x, xv); FMA4(acc[9], a2.y, xv); FMA4(acc[10], a2.z, xv); FMA4(acc[11], a2.w, xv);
    }
    #pragma unroll
    for (int h = 0; h < 12; ++h)
        *(float4*)(yp + (((size_t)k * B + b) * H + h) * C + tid * 4) = acc[h];
}

// ---------------------------------------------------------------------------
// k_yred: y[i] = sum_k yp[k][i]  (float4-wide). grid 576 x 256.
// ---------------------------------------------------------------------------
__global__ __launch_bounds__(256) void k_yred(const float* __restrict__ yp,
                                              float* __restrict__ y) {
    int i = blockIdx.x * 256 + threadIdx.x;   // float4 index, 147456 total
    const float4* src = (const float4*)yp;
    float4 s = make_float4(0.f, 0.f, 0.f, 0.f);
    #pragma unroll
    for (int k = 0; k < 8; ++k) {
        float4 v = src[(size_t)k * 147456 + i];
        s.x += v.x; s.y += v.y; s.z += v.z; s.w += v.w;
    }
    ((float4*)y)[i] = s;
}

// ---------------------------------------------------------------------------
// k_zproj: z[b][c] = y[b,h(c),:] . vW[c,:] + vb[c]*s2[b,h(c)]
// grid (16 btiles, 48 ctiles of 16; h = ct/4), block 256.
// ---------------------------------------------------------------------------
__global__ __launch_bounds__(256) void k_zproj(const float* __restrict__ y,
                                               const float* __restrict__ vW,
                                               const float* __restrict__ vb,
                                               const float* __restrict__ s2,
                                               float* __restrict__ z) {
    __shared__ float ys[4 * C];
    int bt = blockIdx.x, ct = blockIdx.y, tid = threadIdx.x;
    int h = ct >> 2;
    for (int i = tid; i < 768; i += 256) {   // 4 rows x 192 float4
        int bl = i / 192, c4 = i % 192;
        ((float4*)ys)[i] = ((const float4*)(y + (((size_t)(bt * 4 + bl)) * H + h) * C))[c4];
    }
    __syncthreads();
    int w = tid >> 6, lane = tid & 63;
    int b = bt * 4 + w;
    float sv = s2[b * H + h];
    const float* yrow = &ys[w * C];
    for (int cl = 0; cl < 16; ++cl) {
        int c = ct * 16 + cl;
        const float4* wr = (const float4*)(vW + (size_t)c * C + lane * 12);
        const float4* yr = (const float4*)(yrow + lane * 12);
        float acc = 0.f;
        #pragma unroll
        for (int s = 0; s < 3; ++s) {
            float4 a = wr[s], v = yr[s];
            acc += a.x * v.x + a.y * v.y + a.z * v.z + a.w * v.w;
        }
        acc = wave_reduce_add(acc);
        if (lane == 0) z[b * C + c] = acc + vb[c] * sv;
    }
}

// ---------------------------------------------------------------------------
// k_out: out[b][c] = z[b,:] . projW[c,:] + projb[c]
// grid (16 btiles, 48 ctiles of 16), block 256.
// ---------------------------------------------------------------------------
__global__ __launch_bounds__(256) void k_out(const float* __restrict__ z,
                                             const float* __restrict__ pW,
                                             const float* __restrict__ pb,
                                             float* __restrict__ out) {
    __shared__ float zs[4 * C];
    int bt = blockIdx.x, ct = blockIdx.y, tid = threadIdx.x;
    for (int i = tid; i < 768; i += 256)
        ((float4*)zs)[i] = ((const float4*)(z + (size_t)bt * 4 * C))[i];
    __syncthreads();
    int w = tid >> 6, lane = tid & 63;
    int b = bt * 4 + w;
    for (int cl = 0; cl < 16; ++cl) {
        int c = ct * 16 + cl;
        const float4* wr = (const float4*)(pW + (size_t)c * C + lane * 12);
        const float4* zr = (const float4*)(zs + w * C + lane * 12);
        float acc = 0.f;
        #pragma unroll
        for (int s = 0; s < 3; ++s) {
            float4 a = wr[s], v = zr[s];
            acc += a.x * v.x + a.y * v.y + a.z * v.z + a.w * v.w;
        }
        acc = wave_reduce_add(acc);
        if (lane == 0) out[b * C + c] = acc + pb[c];
    }
}

extern "C" void kernel_launch(void* const* d_in, const int* in_sizes, int n_in,
                              void* d_out, int out_size, void* d_ws, size_t ws_size,
                              hipStream_t stream) {
    const float* x    = (const float*)d_in[0];
    const float* qW   = (const float*)d_in[1];
    const float* qb   = (const float*)d_in[2];
    const float* kW   = (const float*)d_in[3];
    const float* kb   = (const float*)d_in[4];
    const float* vW   = (const float*)d_in[5];
    const float* vb   = (const float*)d_in[6];
    const float* w1W  = (const float*)d_in[7];
    const float* w1b  = (const float*)d_in[8];
    const float* w2W  = (const float*)d_in[9];
    const float* w2b  = (const float*)d_in[10];
    const float* pW   = (const float*)d_in[11];
    const float* pb   = (const float*)d_in[12];
    float* out = (float*)d_out;

    float* ws   = (float*)d_ws;
    float* qk   = ws + 0;        // 64*12*768        = 589824
    float* qkb  = ws + 589824;   // 64*12            = 768
    float* q    = ws + 590592;   // 64*768           = 49152
    float* sc   = ws + 639744;   // 64*12*1028       = 789504
    float* y    = sc;            // aliased: sc dead after k_softmix; 589824 <= 789504
    float* a2t  = ws + 1429248;  // 64*1025*12       = 787200
    float* s2   = ws + 2216448;  // 64*12            = 768
    float* yp   = ws + 2217216;  // 8*64*12*768      = 4718592
    float* z    = ws + 6935808;  // 64*768           = 49152
    // total 6984960 floats = 27.9 MB

    k_qproj  <<<dim3(16, 48), 256, 0, stream>>>(x, qW, qb, q);
    k_qk     <<<dim3(16, 12), 256, 0, stream>>>(q, kW, kb, qk, qkb);
    k_scores <<<dim3(17, 64), 256, 0, stream>>>(x, qk, sc);
    k_softmix<<<64, 256, 0, stream>>>(sc, qkb, w1W, w1b, w2W, w2b, a2t, s2);
    k_ysum   <<<dim3(8, 64), 192, 0, stream>>>(x, a2t, yp);
    k_yred   <<<576, 256, 0, stream>>>(yp, y);
    k_zproj  <<<dim3(16, 48), 256, 0, stream>>>(y, vW, vb, s2, z);
    k_out    <<<dim3(16, 48), 256, 0, stream>>>(z, pW, pb, out);
}

// Round 3
// 458.876 us; speedup vs baseline: 1.2918x; 1.0169x over previous
//
#include <hip/hip_runtime.h>

#define B 64
#define N 1025
#define NPAD 1028
#define C 768
#define H 12
#define HD 64

__device__ __forceinline__ float wave_reduce_add(float v) {
    #pragma unroll
    for (int m = 1; m < 64; m <<= 1) v += __shfl_xor(v, m, 64);
    return v;
}

// ---------------------------------------------------------------------------
// k_qproj: q[b][c] = 0.125 * (cls[b] . qW[c,:] + qb[c])
// grid (16 btiles, 48 ctiles of 16), block 256 (4 waves). Wave w = batch.
// ---------------------------------------------------------------------------
__global__ __launch_bounds__(256) void k_qproj(const float* __restrict__ x,
                                               const float* __restrict__ qW,
                                               const float* __restrict__ qb,
                                               float* __restrict__ qout) {
    __shared__ float cls[4 * C];
    int bt = blockIdx.x, ct = blockIdx.y, tid = threadIdx.x;
    for (int i = tid; i < 768; i += 256) {   // 768 float4 = 4 rows x 192
        int bl = i / 192, c4 = i % 192;
        ((float4*)cls)[i] = ((const float4*)(x + (size_t)(bt * 4 + bl) * N * C))[c4];
    }
    __syncthreads();
    int w = tid >> 6, lane = tid & 63;
    int b = bt * 4 + w;
    const float* clsrow = &cls[w * C];
    for (int cl = 0; cl < 16; ++cl) {
        int c = ct * 16 + cl;
        const float4* wr = (const float4*)(qW + (size_t)c * C + lane * 12);
        const float4* xr = (const float4*)(clsrow + lane * 12);
        float acc = 0.f;
        #pragma unroll
        for (int s = 0; s < 3; ++s) {
            float4 a = wr[s], v = xr[s];
            acc += a.x * v.x + a.y * v.y + a.z * v.z + a.w * v.w;
        }
        acc = wave_reduce_add(acc);
        if (lane == 0) qout[b * C + c] = 0.125f * (acc + qb[c]);
    }
}

// ---------------------------------------------------------------------------
// k_qk: qk[b][h][c'] = sum_{i<64} q[b][h*64+i] * kW[h*64+i][c']
//       qkb[b][h]    = sum_{i<64} q[b][h*64+i] * kb[h*64+i]
// grid (16 btiles, 12 heads), block 256.
// ---------------------------------------------------------------------------
__global__ __launch_bounds__(256) void k_qk(const float* __restrict__ q,
                                            const float* __restrict__ kW,
                                            const float* __restrict__ kb,
                                            float* __restrict__ qk,
                                            float* __restrict__ qkb) {
    int bt = blockIdx.x, h = blockIdx.y, tid = threadIdx.x;
    if (tid < 192) {
        float4 acc[4] = {};
        #pragma unroll 4
        for (int i = 0; i < HD; ++i) {
            int row = h * HD + i;
            float4 kv = *(const float4*)(kW + (size_t)row * C + tid * 4);
            #pragma unroll
            for (int bl = 0; bl < 4; ++bl) {
                float qv = q[(bt * 4 + bl) * C + row];  // uniform -> s_load
                acc[bl].x += qv * kv.x; acc[bl].y += qv * kv.y;
                acc[bl].z += qv * kv.z; acc[bl].w += qv * kv.w;
            }
        }
        #pragma unroll
        for (int bl = 0; bl < 4; ++bl) {
            int b = bt * 4 + bl;
            *(float4*)(qk + ((size_t)b * H + h) * C + tid * 4) = acc[bl];
        }
    }
    int w = tid >> 6, lane = tid & 63;
    int b = bt * 4 + w;
    float v = q[b * C + h * HD + lane] * kb[h * HD + lane];
    v = wave_reduce_add(v);
    if (lane == 0) qkb[b * H + h] = v;
}

// ---------------------------------------------------------------------------
// k_scores: sc[b][h][n] = x[b,n,:] . qk[b,h,:]   (qkb bias added in k_mix1)
// x pass 1. grid (17 row-tiles, 64 b), block 256. qk[b] in LDS (36 KB).
// ---------------------------------------------------------------------------
__global__ __launch_bounds__(256) void k_scores(const float* __restrict__ x,
                                                const float* __restrict__ qk,
                                                float* __restrict__ sc) {
    __shared__ float qs[12 * C];   // 36 KB
    int tile = blockIdx.x, b = blockIdx.y, tid = threadIdx.x;
    const float4* qksrc = (const float4*)(qk + (size_t)b * H * C);
    for (int i = tid; i < 2304; i += 256) ((float4*)qs)[i] = qksrc[i];
    __syncthreads();
    int w = tid >> 6, lane = tid & 63;
    int c16 = lane & 15, r = lane >> 4;
    int rowbase = tile * 64 + w * 16 + r * 4;
    const float* xb = x + (size_t)b * N * C;
    float acc[4][12] = {};
    for (int cc = 0; cc < C; cc += 128) {
        int c0 = cc + c16 * 4, c1 = c0 + 64;
        float4 xv0[4], xv1[4];
        #pragma unroll
        for (int j = 0; j < 4; ++j) {
            int row = rowbase + j;
            const float* xr = xb + (size_t)row * C;
            xv0[j] = (row < N) ? *(const float4*)(xr + c0) : make_float4(0.f,0.f,0.f,0.f);
            xv1[j] = (row < N) ? *(const float4*)(xr + c1) : make_float4(0.f,0.f,0.f,0.f);
        }
        #pragma unroll
        for (int h = 0; h < 12; ++h) {
            float4 q0 = *(const float4*)(qs + h * C + c0);
            float4 q1 = *(const float4*)(qs + h * C + c1);
            #pragma unroll
            for (int j = 0; j < 4; ++j) {
                acc[j][h] += xv0[j].x * q0.x + xv0[j].y * q0.y +
                             xv0[j].z * q0.z + xv0[j].w * q0.w;
                acc[j][h] += xv1[j].x * q1.x + xv1[j].y * q1.y +
                             xv1[j].z * q1.z + xv1[j].w * q1.w;
            }
        }
    }
    #pragma unroll
    for (int j = 0; j < 4; ++j)
        #pragma unroll
        for (int h = 0; h < 12; ++h) {
            float v = acc[j][h];
            v += __shfl_xor(v, 1); v += __shfl_xor(v, 2);
            v += __shfl_xor(v, 4); v += __shfl_xor(v, 8);
            acc[j][h] = v;
        }
    if (c16 == 0) {
        #pragma unroll
        for (int j = 0; j < 4; ++j) {
            int row = rowbase + j;
            if (row < N) {
                #pragma unroll
                for (int h = 0; h < 12; ++h)
                    sc[((size_t)b * H + h) * NPAD + row] = acc[j][h];
            }
        }
    }
}

// ---------------------------------------------------------------------------
// k_mix1: per (chunk k, batch b): a1 = (s+qkb) + w1W@(s+qkb) + w1b, written
// in-place to sc; emits per-chunk per-head max and sum(exp(a1-max)) stats.
// grid (8, 64), block 256 (thread = one n).
// ---------------------------------------------------------------------------
__global__ __launch_bounds__(256) void k_mix1(float* __restrict__ sc,
                                              const float* __restrict__ qkbias,
                                              const float* __restrict__ w1W,
                                              const float* __restrict__ w1b,
                                              float* __restrict__ mstat,
                                              float* __restrict__ sstat) {
    __shared__ float w1s[144], w1bs[12], qbs[12];
    __shared__ float red[4][12];
    __shared__ float mg[12];
    int kk = blockIdx.x, b = blockIdx.y, tid = threadIdx.x;
    int nn = (kk == 7) ? 129 : 128;
    int n = kk * 128 + tid;
    if (tid < 144) w1s[tid] = w1W[tid];
    if (tid < 12)  { w1bs[tid] = w1b[tid]; qbs[tid] = qkbias[b * 12 + tid]; }
    __syncthreads();
    bool act = tid < nn;
    float o[12];
    if (act) {
        float s_[12];
        #pragma unroll
        for (int h = 0; h < 12; ++h)
            s_[h] = sc[((size_t)b * H + h) * NPAD + n] + qbs[h];
        #pragma unroll
        for (int g = 0; g < 12; ++g) {
            float a = s_[g] + w1bs[g];
            #pragma unroll
            for (int h = 0; h < 12; ++h) a += w1s[g * 12 + h] * s_[h];
            o[g] = a;
        }
        #pragma unroll
        for (int g = 0; g < 12; ++g)
            sc[((size_t)b * H + g) * NPAD + n] = o[g];
    } else {
        #pragma unroll
        for (int g = 0; g < 12; ++g) o[g] = -3e38f;
    }
    int w = tid >> 6, lane = tid & 63;
    #pragma unroll
    for (int g = 0; g < 12; ++g) {
        float v = o[g];
        #pragma unroll
        for (int m = 1; m < 64; m <<= 1) v = fmaxf(v, __shfl_xor(v, m, 64));
        if (lane == 0) red[w][g] = v;
    }
    __syncthreads();
    if (tid < 12)
        mg[tid] = fmaxf(fmaxf(red[0][tid], red[1][tid]),
                        fmaxf(red[2][tid], red[3][tid]));
    __syncthreads();
    #pragma unroll
    for (int g = 0; g < 12; ++g) {
        float e = act ? __expf(o[g] - mg[g]) : 0.f;
        e = wave_reduce_add(e);
        if (lane == 0) red[w][g] = e;
    }
    __syncthreads();
    if (tid < 12) {
        mstat[((size_t)b * 8 + kk) * 12 + tid] = mg[tid];
        sstat[((size_t)b * 8 + kk) * 12 + tid] =
            red[0][tid] + red[1][tid] + red[2][tid] + red[3][tid];
    }
}

// ---------------------------------------------------------------------------
// k_ysum: combines chunk stats -> softmax p = exp(a1-m)/S, mix2 in LDS,
// then yp[k][b][h][c] = sum_{n in chunk} a2[h][n] * x[b][n][c].
// x pass 2. grid (8, 64), block 192.
// ---------------------------------------------------------------------------
#define FMA4(d, s, xv) { d.x += (s) * xv.x; d.y += (s) * xv.y; d.z += (s) * xv.z; d.w += (s) * xv.w; }
__global__ __launch_bounds__(192) void k_ysum(const float* __restrict__ x,
                                              const float* __restrict__ sc,
                                              const float* __restrict__ mstat,
                                              const float* __restrict__ sstat,
                                              const float* __restrict__ w2W,
                                              const float* __restrict__ w2b,
                                              float* __restrict__ yp) {
    __shared__ float as_[129 * 12];
    __shared__ float w2s[144], w2bs[12], msh[12], ish[12];
    int k = blockIdx.x, b = blockIdx.y, tid = threadIdx.x;
    int nlo = k * 128, nn = (k == 7) ? 129 : 128;
    if (tid < 144) w2s[tid] = w2W[tid];
    if (tid < 12) {
        w2bs[tid] = w2b[tid];
        float m = -3e38f, mv[8];
        #pragma unroll
        for (int kk = 0; kk < 8; ++kk) {
            mv[kk] = mstat[((size_t)b * 8 + kk) * 12 + tid];
            m = fmaxf(m, mv[kk]);
        }
        float S = 0.f;
        #pragma unroll
        for (int kk = 0; kk < 8; ++kk)
            S += sstat[((size_t)b * 8 + kk) * 12 + tid] * __expf(mv[kk] - m);
        msh[tid] = m; ish[tid] = 1.f / S;
    }
    __syncthreads();
    if (tid < nn) {
        int n = nlo + tid;
        float p[12];
        #pragma unroll
        for (int h = 0; h < 12; ++h)
            p[h] = __expf(sc[((size_t)b * H + h) * NPAD + n] - msh[h]) * ish[h];
        #pragma unroll
        for (int g = 0; g < 12; ++g) {
            float a = p[g] + w2bs[g];
            #pragma unroll
            for (int h = 0; h < 12; ++h) a += w2s[g * 12 + h] * p[h];
            as_[tid * 12 + g] = a;
        }
    }
    __syncthreads();
    const float* xb = x + ((size_t)b * N + nlo) * C + tid * 4;
    float4 acc[12] = {};
    int n = 0;
    for (; n + 4 <= nn; n += 4) {
        float4 xv[4];
        #pragma unroll
        for (int u = 0; u < 4; ++u)
            xv[u] = *(const float4*)(xb + (size_t)(n + u) * C);
        #pragma unroll
        for (int u = 0; u < 4; ++u) {
            const float4* ar = (const float4*)(as_ + (n + u) * 12);
            float4 a0 = ar[0], a1 = ar[1], a2 = ar[2];
            FMA4(acc[0], a0.x, xv[u]); FMA4(acc[1], a0.y, xv[u]); FMA4(acc[2], a0.z, xv[u]); FMA4(acc[3], a0.w, xv[u]);
            FMA4(acc[4], a1.x, xv[u]); FMA4(acc[5], a1.y, xv[u]); FMA4(acc[6], a1.z, xv[u]); FMA4(acc[7], a1.w, xv[u]);
            FMA4(acc[8], a2.x, xv[u]); FMA4(acc[9], a2.y, xv[u]); FMA4(acc[10], a2.z, xv[u]); FMA4(acc[11], a2.w, xv[u]);
        }
    }
    for (; n < nn; ++n) {
        float4 xv = *(const float4*)(xb + (size_t)n * C);
        const float4* ar = (const float4*)(as_ + n * 12);
        float4 a0 = ar[0], a1 = ar[1], a2 = ar[2];
        FMA4(acc[0], a0.x, xv); FMA4(acc[1], a0.y, xv); FMA4(acc[2], a0.z, xv); FMA4(acc[3], a0.w, xv);
        FMA4(acc[4], a1.x, xv); FMA4(acc[5], a1.y, xv); FMA4(acc[6], a1.z, xv); FMA4(acc[7], a1.w, xv);
        FMA4(acc[8], a2.x, xv); FMA4(acc[9], a2.y, xv); FMA4(acc[10], a2.z, xv); FMA4(acc[11], a2.w, xv);
    }
    #pragma unroll
    for (int h = 0; h < 12; ++h)
        *(float4*)(yp + (((size_t)k * B + b) * H + h) * C + tid * 4) = acc[h];
}

// ---------------------------------------------------------------------------
// k_zproj: ybar = sum_k yp[k]; z[b][c] = ybar[b,h(c),:] . vW[c,:] + vb[c]*sv,
// sv = 1 + rowsum(w2W)[h] + N*w2b[h] (softmax rows sum to 1 -> closed form).
// grid (16 btiles, 12 heads), block 256.
// ---------------------------------------------------------------------------
__global__ __launch_bounds__(256) void k_zproj(const float* __restrict__ yp,
                                               const float* __restrict__ vW,
                                               const float* __restrict__ vb,
                                               const float* __restrict__ w2W,
                                               const float* __restrict__ w2b,
                                               float* __restrict__ z) {
    __shared__ float ys[4 * C];
    int bt = blockIdx.x, h = blockIdx.y, tid = threadIdx.x;
    for (int i = tid; i < 768; i += 256) {   // 4 rows x 192 float4
        int bl = i / 192, c4 = i % 192;
        int b = bt * 4 + bl;
        float4 s = make_float4(0.f, 0.f, 0.f, 0.f);
        #pragma unroll
        for (int k = 0; k < 8; ++k) {
            float4 v = ((const float4*)(yp + (((size_t)k * B + b) * H + h) * C))[c4];
            s.x += v.x; s.y += v.y; s.z += v.z; s.w += v.w;
        }
        ((float4*)ys)[i] = s;
    }
    __syncthreads();
    float sv = 1.f + 1025.f * w2b[h];
    #pragma unroll
    for (int j = 0; j < 12; ++j) sv += w2W[h * 12 + j];
    int w = tid >> 6, lane = tid & 63;
    int b = bt * 4 + w;
    const float* yrow = &ys[w * C];
    for (int cl = 0; cl < 64; ++cl) {
        int c = h * 64 + cl;
        const float4* wr = (const float4*)(vW + (size_t)c * C + lane * 12);
        const float4* yr = (const float4*)(yrow + lane * 12);
        float acc = 0.f;
        #pragma unroll
        for (int s = 0; s < 3; ++s) {
            float4 a = wr[s], v = yr[s];
            acc += a.x * v.x + a.y * v.y + a.z * v.z + a.w * v.w;
        }
        acc = wave_reduce_add(acc);
        if (lane == 0) z[b * C + c] = acc + vb[c] * sv;
    }
}

// ---------------------------------------------------------------------------
// k_out: out[b][c] = z[b,:] . projW[c,:] + projb[c]
// grid (16 btiles, 48 ctiles of 16), block 256.
// ---------------------------------------------------------------------------
__global__ __launch_bounds__(256) void k_out(const float* __restrict__ z,
                                             const float* __restrict__ pW,
                                             const float* __restrict__ pb,
                                             float* __restrict__ out) {
    __shared__ float zs[4 * C];
    int bt = blockIdx.x, ct = blockIdx.y, tid = threadIdx.x;
    for (int i = tid; i < 768; i += 256)
        ((float4*)zs)[i] = ((const float4*)(z + (size_t)bt * 4 * C))[i];
    __syncthreads();
    int w = tid >> 6, lane = tid & 63;
    int b = bt * 4 + w;
    for (int cl = 0; cl < 16; ++cl) {
        int c = ct * 16 + cl;
        const float4* wr = (const float4*)(pW + (size_t)c * C + lane * 12);
        const float4* zr = (const float4*)(zs + w * C + lane * 12);
        float acc = 0.f;
        #pragma unroll
        for (int s = 0; s < 3; ++s) {
            float4 a = wr[s], v = zr[s];
            acc += a.x * v.x + a.y * v.y + a.z * v.z + a.w * v.w;
        }
        acc = wave_reduce_add(acc);
        if (lane == 0) out[b * C + c] = acc + pb[c];
    }
}

extern "C" void kernel_launch(void* const* d_in, const int* in_sizes, int n_in,
                              void* d_out, int out_size, void* d_ws, size_t ws_size,
                              hipStream_t stream) {
    const float* x    = (const float*)d_in[0];
    const float* qW   = (const float*)d_in[1];
    const float* qb   = (const float*)d_in[2];
    const float* kW   = (const float*)d_in[3];
    const float* kb   = (const float*)d_in[4];
    const float* vW   = (const float*)d_in[5];
    const float* vb   = (const float*)d_in[6];
    const float* w1W  = (const float*)d_in[7];
    const float* w1b  = (const float*)d_in[8];
    const float* w2W  = (const float*)d_in[9];
    const float* w2b  = (const float*)d_in[10];
    const float* pW   = (const float*)d_in[11];
    const float* pb   = (const float*)d_in[12];
    float* out = (float*)d_out;

    float* ws    = (float*)d_ws;
    float* qk    = ws + 0;        // 64*12*768  = 589824
    float* qkb   = ws + 589824;   // 768
    float* q     = ws + 590592;   // 49152
    float* sc    = ws + 639744;   // 64*12*1028 = 789504 (scores, then a1 in place)
    float* yp    = ws + 1429248;  // 8*64*12*768 = 4718592
    float* z     = ws + 6147840;  // 49152
    float* mstat = ws + 6196992;  // 64*8*12 = 6144
    float* sstat = ws + 6203136;  // 6144
    // total 6209280 floats = 24.8 MB

    k_qproj <<<dim3(16, 48), 256, 0, stream>>>(x, qW, qb, q);
    k_qk    <<<dim3(16, 12), 256, 0, stream>>>(q, kW, kb, qk, qkb);
    k_scores<<<dim3(17, 64), 256, 0, stream>>>(x, qk, sc);
    k_mix1  <<<dim3(8, 64), 256, 0, stream>>>(sc, qkb, w1W, w1b, mstat, sstat);
    k_ysum  <<<dim3(8, 64), 192, 0, stream>>>(x, sc, mstat, sstat, w2W, w2b, yp);
    k_zproj <<<dim3(16, 12), 256, 0, stream>>>(yp, vW, vb, w2W, w2b, z);
    k_out   <<<dim3(16, 48), 256, 0, stream>>>(z, pW, pb, out);
}